// Round 1
// baseline (952.439 us; speedup 1.0000x reference)
//
#include <hip/hip_runtime.h>
#include <hip/hip_bf16.h>

// AxialSoftAttention: B=4, C=64, F=256, T=384, DC=16
// Pipeline: fqkv conv+BN+PReLU -> f-attn (over F, per (b,t)) -> tqk conv+BN+PReLU
//           -> causal t-attn (over T, per (b,f), values = f_out) -> proj conv+BN+PReLU + residual

#define B_   4
#define CIN  64
#define F_   256
#define T_   384
#define DC_  16
#define FQ_  48
#define TQ_  32
#define SP_  (F_ * T_)          // 98304 spatial per batch
#define EPSF 1e-5f

// ---------------- Kernel A: fused fqkv + tqk 1x1 conv + BN + PReLU ----------------
__global__ __launch_bounds__(256) void k_conv(
    const float* __restrict__ x,
    const float* __restrict__ wf, const float* __restrict__ gf, const float* __restrict__ bf,
    const float* __restrict__ mf, const float* __restrict__ vf, const float* __restrict__ af,
    const float* __restrict__ wt, const float* __restrict__ gt, const float* __restrict__ bt,
    const float* __restrict__ mt, const float* __restrict__ vt, const float* __restrict__ at,
    float* __restrict__ fqkv, float* __restrict__ tqk)
{
    __shared__ float s_wf[FQ_ * 64];
    __shared__ float s_wt[TQ_ * 64];
    __shared__ float sc_f[FQ_], bi_f[FQ_], al_f[FQ_];
    __shared__ float sc_t[TQ_], bi_t[TQ_], al_t[TQ_];

    const int tid = threadIdx.x;
    for (int i = tid; i < FQ_ * 64; i += 256) s_wf[i] = wf[i];
    for (int i = tid; i < TQ_ * 64; i += 256) s_wt[i] = wt[i];
    if (tid < FQ_) {
        float s = gf[tid] * rsqrtf(vf[tid] + EPSF);
        sc_f[tid] = s; bi_f[tid] = bf[tid] - mf[tid] * s; al_f[tid] = af[tid];
    } else if (tid >= 64 && tid < 64 + TQ_) {
        int c = tid - 64;
        float s = gt[c] * rsqrtf(vt[c] + EPSF);
        sc_t[c] = s; bi_t[c] = bt[c] - mt[c] * s; al_t[c] = at[c];
    }
    __syncthreads();

    const int pos = blockIdx.x * 256 + tid;   // [0, B*SP)
    const int b = pos / SP_;
    const int rem = pos - b * SP_;

    const float* xp = x + b * (CIN * SP_) + rem;
    float xr[64];
#pragma unroll
    for (int c = 0; c < 64; ++c) xr[c] = xp[c * SP_];

    float* fq = fqkv + b * (FQ_ * SP_) + rem;
    for (int o = 0; o < FQ_; ++o) {
        float acc = 0.f;
#pragma unroll
        for (int c = 0; c < 64; ++c) acc += s_wf[o * 64 + c] * xr[c];
        float xn = acc * sc_f[o] + bi_f[o];
        fq[o * SP_] = xn >= 0.f ? xn : al_f[o] * xn;
    }
    float* tq = tqk + b * (TQ_ * SP_) + rem;
    for (int o = 0; o < TQ_; ++o) {
        float acc = 0.f;
#pragma unroll
        for (int c = 0; c < 64; ++c) acc += s_wt[o * 64 + c] * xr[c];
        float xn = acc * sc_t[o] + bi_t[o];
        tq[o * SP_] = xn >= 0.f ? xn : al_t[o] * xn;
    }
}

// ---------------- Kernel B: f-attention, one block per (b, t) ----------------
// f_score[f,y] = 0.25 * sum_c qf[c,f]*kf[c,y]; softmax over y; f_out[c,f] = sum_y p * v[c,y]
__global__ __launch_bounds__(256) void k_fattn(
    const float* __restrict__ fqkv, float* __restrict__ fout)
{
    __shared__ float sq[16][F_];
    __shared__ float sk[16][F_];
    __shared__ float sv[16][F_];

    const int b = blockIdx.x / T_;
    const int t = blockIdx.x - b * T_;
    const int tid = threadIdx.x;

    const float* src = fqkv + b * (FQ_ * SP_) + t;
    for (int i = tid; i < FQ_ * F_; i += 256) {
        int c = i >> 8;
        int f = i & (F_ - 1);
        float val = src[(c * F_ + f) * T_];
        if (c < 16)      sq[c][f]      = val;
        else if (c < 32) sk[c - 16][f] = val;
        else             sv[c - 32][f] = val;
    }
    __syncthreads();

    const int f = tid;
    float q[16];
#pragma unroll
    for (int c = 0; c < 16; ++c) q[c] = sq[c][f];

    float m = -3.0e38f, l = 0.f;
    float acc[16];
#pragma unroll
    for (int c = 0; c < 16; ++c) acc[c] = 0.f;

    for (int y = 0; y < F_; ++y) {
        float s = 0.f;
#pragma unroll
        for (int c = 0; c < 16; ++c) s += q[c] * sk[c][y];
        s *= 0.25f;
        if (s > m) {
            float r = __expf(m - s);
#pragma unroll
            for (int c = 0; c < 16; ++c) acc[c] *= r;
            l *= r; m = s;
        }
        float p = __expf(s - m);
        l += p;
#pragma unroll
        for (int c = 0; c < 16; ++c) acc[c] += p * sv[c][y];
    }
    float inv = 1.f / l;
    float* dst = fout + b * (DC_ * SP_) + f * T_ + t;
#pragma unroll
    for (int c = 0; c < 16; ++c) dst[c * SP_] = acc[c] * inv;
}

// ---------------- Kernel C: causal t-attention, one block per (b, f) ----------------
// t_score[t,y] = 0.25 * sum_c qt[c,t]*kt[c,y], y<=t; softmax; t_out[c,t] = sum_y p * f_out[c,y]
__global__ __launch_bounds__(384) void k_tattn(
    const float* __restrict__ tqk, const float* __restrict__ fout, float* __restrict__ tout)
{
    __shared__ float sq[16][T_];
    __shared__ float sk[16][T_];
    __shared__ float sf[16][T_];

    const int b = blockIdx.x / F_;
    const int f = blockIdx.x - b * F_;
    const int tid = threadIdx.x;

    const float* src = tqk + b * (TQ_ * SP_) + f * T_;
    for (int i = tid; i < TQ_ * T_; i += 384) {
        int c = i / T_;
        int t = i - c * T_;
        float val = src[c * SP_ + t];
        if (c < 16) sq[c][t] = val; else sk[c - 16][t] = val;
    }
    const float* srcf = fout + b * (DC_ * SP_) + f * T_;
    for (int i = tid; i < DC_ * T_; i += 384) {
        int c = i / T_;
        int t = i - c * T_;
        sf[c][t] = srcf[c * SP_ + t];
    }
    __syncthreads();

    const int t = tid;
    float q[16];
#pragma unroll
    for (int c = 0; c < 16; ++c) q[c] = sq[c][t];

    float m = -3.0e38f, l = 0.f;
    float acc[16];
#pragma unroll
    for (int c = 0; c < 16; ++c) acc[c] = 0.f;

    for (int y = 0; y <= t; ++y) {
        float s = 0.f;
#pragma unroll
        for (int c = 0; c < 16; ++c) s += q[c] * sk[c][y];
        s *= 0.25f;
        if (s > m) {
            float r = __expf(m - s);
#pragma unroll
            for (int c = 0; c < 16; ++c) acc[c] *= r;
            l *= r; m = s;
        }
        float p = __expf(s - m);
        l += p;
#pragma unroll
        for (int c = 0; c < 16; ++c) acc[c] += p * sf[c][y];
    }
    float inv = 1.f / l;
    float* dst = tout + b * (DC_ * SP_) + f * T_ + t;
#pragma unroll
    for (int c = 0; c < 16; ++c) dst[c * SP_] = acc[c] * inv;
}

// ---------------- Kernel D: proj conv + BN + PReLU + residual ----------------
__global__ __launch_bounds__(256) void k_proj(
    const float* __restrict__ tout, const float* __restrict__ x,
    const float* __restrict__ pw, const float* __restrict__ g, const float* __restrict__ be,
    const float* __restrict__ mn, const float* __restrict__ va, const float* __restrict__ al,
    float* __restrict__ out)
{
    __shared__ float s_w[64 * 16];
    __shared__ float sc[64], bi[64], alp[64];

    const int tid = threadIdx.x;
    for (int i = tid; i < 64 * 16; i += 256) s_w[i] = pw[i];
    if (tid < 64) {
        float s = g[tid] * rsqrtf(va[tid] + EPSF);
        sc[tid] = s; bi[tid] = be[tid] - mn[tid] * s; alp[tid] = al[tid];
    }
    __syncthreads();

    const int pos = blockIdx.x * 256 + tid;
    const int b = pos / SP_;
    const int rem = pos - b * SP_;

    const float* tp = tout + b * (DC_ * SP_) + rem;
    float tr[16];
#pragma unroll
    for (int c = 0; c < 16; ++c) tr[c] = tp[c * SP_];

    const float* xp = x + b * (CIN * SP_) + rem;
    float* op = out + b * (CIN * SP_) + rem;
    for (int o = 0; o < 64; ++o) {
        float acc = 0.f;
#pragma unroll
        for (int c = 0; c < 16; ++c) acc += s_w[o * 16 + c] * tr[c];
        float xn = acc * sc[o] + bi[o];
        xn = xn >= 0.f ? xn : alp[o] * xn;
        op[o * SP_] = xn + xp[o * SP_];
    }
}

extern "C" void kernel_launch(void* const* d_in, const int* in_sizes, int n_in,
                              void* d_out, int out_size, void* d_ws, size_t ws_size,
                              hipStream_t stream) {
    const float* x          = (const float*)d_in[0];
    const float* fqkv_w     = (const float*)d_in[1];
    const float* fqkv_gamma = (const float*)d_in[2];
    const float* fqkv_beta  = (const float*)d_in[3];
    const float* fqkv_mean  = (const float*)d_in[4];
    const float* fqkv_var   = (const float*)d_in[5];
    const float* fqkv_alpha = (const float*)d_in[6];
    const float* tqk_w      = (const float*)d_in[7];
    const float* tqk_gamma  = (const float*)d_in[8];
    const float* tqk_beta   = (const float*)d_in[9];
    const float* tqk_mean   = (const float*)d_in[10];
    const float* tqk_var    = (const float*)d_in[11];
    const float* tqk_alpha  = (const float*)d_in[12];
    const float* proj_w     = (const float*)d_in[13];
    const float* proj_gamma = (const float*)d_in[14];
    const float* proj_beta  = (const float*)d_in[15];
    const float* proj_mean  = (const float*)d_in[16];
    const float* proj_var   = (const float*)d_in[17];
    const float* proj_alpha = (const float*)d_in[18];

    float* ws   = (float*)d_ws;
    float* fqkv = ws;                                   // B*48*SP = 18,874,368 floats
    float* tqk  = fqkv + (size_t)B_ * FQ_ * SP_;        // B*32*SP = 12,582,912
    float* fout = tqk  + (size_t)B_ * TQ_ * SP_;        // B*16*SP =  6,291,456
    float* tout = fout + (size_t)B_ * DC_ * SP_;        // B*16*SP =  6,291,456

    float* out = (float*)d_out;

    k_conv<<<(B_ * SP_) / 256, 256, 0, stream>>>(
        x, fqkv_w, fqkv_gamma, fqkv_beta, fqkv_mean, fqkv_var, fqkv_alpha,
        tqk_w, tqk_gamma, tqk_beta, tqk_mean, tqk_var, tqk_alpha, fqkv, tqk);

    k_fattn<<<B_ * T_, 256, 0, stream>>>(fqkv, fout);

    k_tattn<<<B_ * F_, 384, 0, stream>>>(tqk, fout, tout);

    k_proj<<<(B_ * SP_) / 256, 256, 0, stream>>>(
        tout, x, proj_w, proj_gamma, proj_beta, proj_mean, proj_var, proj_alpha, out);
}

// Round 2
// 748.991 us; speedup vs baseline: 1.2716x; 1.2716x over previous
//
#include <hip/hip_runtime.h>
#include <hip/hip_bf16.h>

// AxialSoftAttention: B=4, C=64, F=256, T=384, DC=16
// Pipeline (all intermediates bf16-packed, transposed at the producer):
//  k_conv : x -> fqkvT [b][t][{q,k,v}][f=256][16c] bf16   (36 MB)
//           x -> tqkT  [b][f][{q,k}][t=384][16c]  bf16   (24 MB)
//  k_fattn: fqkvT -> foutD [b][f][t=384][16c] bf16        (12 MB)
//  k_tattn: tqkT,foutD -> tout [b][16][F][T] fp32         (24 MB)
//  k_proj : tout,x -> out (proj conv + BN + PReLU + residual)

#define B_   4
#define CIN  64
#define F_   256
#define T_   384
#define DC_  16
#define SP_  (F_ * T_)
#define EPSF 1e-5f

__device__ __forceinline__ unsigned int bf16rne(float f) {
    unsigned int u = __float_as_uint(f);
    return (u + 0x7fffu + ((u >> 16) & 1u)) >> 16;
}

// ---------------- Kernel A: conv + BN + PReLU + transpose-to-bf16 ----------------
// block: 256 threads = 4 f x 64 t tile.  grid: B * (F/4) * (T/64) = 1536
__global__ __launch_bounds__(256) void k_conv(
    const float* __restrict__ x,
    const float* __restrict__ wf, const float* __restrict__ gf, const float* __restrict__ bf,
    const float* __restrict__ mf, const float* __restrict__ vf, const float* __restrict__ af,
    const float* __restrict__ wt, const float* __restrict__ gt, const float* __restrict__ bt,
    const float* __restrict__ mt, const float* __restrict__ vt, const float* __restrict__ at,
    unsigned int* __restrict__ fqkvT, unsigned int* __restrict__ tqkT)
{
    __shared__ float tile[16 * 260];   // [c][ff][tt] stride: c*260 + ff*65 + tt (padded)

    const int bid = blockIdx.x;
    const int t0 = (bid % 6) * 64;
    const int f0 = ((bid / 6) & 63) * 4;
    const int b  = bid / 384;
    const int ff = threadIdx.x >> 6;
    const int tt = threadIdx.x & 63;
    const int f = f0 + ff, t = t0 + tt;

    const float* xp = x + (size_t)b * CIN * SP_ + (size_t)f * T_ + t;
    float xr[64];
#pragma unroll
    for (int c = 0; c < 64; ++c) xr[c] = xp[(size_t)c * SP_];

    // 5 sections: 0,1,2 = fqkv q/k/v ; 3,4 = tqk q/k
    for (int sec = 0; sec < 5; ++sec) {
        const bool isF = sec < 3;
        const float* w  = isF ? wf : wt;
        const float* g  = isF ? gf : gt;
        const float* be = isF ? bf : bt;
        const float* mn = isF ? mf : mt;
        const float* va = isF ? vf : vt;
        const float* al = isF ? af : at;
        const int ob = isF ? sec * 16 : (sec - 3) * 16;

        float acc[16];
#pragma unroll
        for (int i = 0; i < 16; ++i) {
            const float* wr = w + (size_t)(ob + i) * 64;
            float a = 0.f;
#pragma unroll
            for (int c = 0; c < 64; ++c) a += wr[c] * xr[c];
            float s  = g[ob + i] * rsqrtf(va[ob + i] + EPSF);
            float xn = a * s + (be[ob + i] - mn[ob + i] * s);
            acc[i] = xn >= 0.f ? xn : al[ob + i] * xn;
        }

        __syncthreads();   // previous section's writeout done reading tile
#pragma unroll
        for (int i = 0; i < 16; ++i) tile[i * 260 + ff * 65 + tt] = acc[i];
        __syncthreads();

        if (isF) {
            // fqkvT[(b*T+t)*6144 + sec*2048 + (f0+ff)*8 + cu], per tt: 32 contig uints
            for (int j = threadIdx.x; j < 2048; j += 256) {
                int wtt = j >> 5;
                int r   = j & 31;
                int wff = r >> 3;
                int cu  = r & 7;
                unsigned int lo = bf16rne(tile[(2 * cu) * 260 + wff * 65 + wtt]);
                unsigned int hi = bf16rne(tile[(2 * cu + 1) * 260 + wff * 65 + wtt]);
                fqkvT[(size_t)(b * T_ + t0 + wtt) * 6144 + sec * 2048 + (f0 + wff) * 8 + cu] =
                    lo | (hi << 16);
            }
        } else {
            // tqkT[(b*256+f)*6144 + tsec*3072 + t*8 + cu], per ff: 512 contig uints
            const int tsec = sec - 3;
            for (int j = threadIdx.x; j < 2048; j += 256) {
                int wff = j >> 9;
                int r   = j & 511;
                int wtt = r >> 3;
                int cu  = r & 7;
                unsigned int lo = bf16rne(tile[(2 * cu) * 260 + wff * 65 + wtt]);
                unsigned int hi = bf16rne(tile[(2 * cu + 1) * 260 + wff * 65 + wtt]);
                tqkT[(size_t)(b * F_ + f0 + wff) * 6144 + tsec * 3072 + (t0 + wtt) * 8 + cu] =
                    lo | (hi << 16);
            }
        }
    }
}

// ---------------- Kernel B: f-attention, one block per (b,t) ----------------
__global__ __launch_bounds__(256) void k_fattn(
    const unsigned int* __restrict__ fqkvT, unsigned int* __restrict__ foutD)
{
    __shared__ float lds[12288];   // q[0..4096) k[4096..8192) v[8192..12288), each [y][16c]

    const int bt = blockIdx.x;
    const unsigned int* src = fqkvT + (size_t)bt * 6144;
    for (int i = threadIdx.x; i < 6144; i += 256) {
        unsigned int u = src[i];
        float2 w2;
        w2.x = __uint_as_float(u << 16);
        w2.y = __uint_as_float(u & 0xffff0000u);
        *(float2*)&lds[2 * i] = w2;
    }
    __syncthreads();

    const int f = threadIdx.x;
    float q[16];
#pragma unroll
    for (int c = 0; c < 16; ++c) q[c] = lds[f * 16 + c];

    const float* kb = lds + 4096;
    const float* vb = lds + 8192;

    float m = -1e30f, l = 0.f;
    float acc[16];
#pragma unroll
    for (int c = 0; c < 16; ++c) acc[c] = 0.f;

    for (int y = 0; y < F_; ++y) {
        const float4* kr = (const float4*)(kb + y * 16);
        float4 k0 = kr[0], k1 = kr[1], k2 = kr[2], k3 = kr[3];
        float s = q[0] * k0.x + q[1] * k0.y + q[2] * k0.z + q[3] * k0.w
                + q[4] * k1.x + q[5] * k1.y + q[6] * k1.z + q[7] * k1.w
                + q[8] * k2.x + q[9] * k2.y + q[10] * k2.z + q[11] * k2.w
                + q[12] * k3.x + q[13] * k3.y + q[14] * k3.z + q[15] * k3.w;
        s *= 0.25f;
        if (s > m) {
            float r = __expf(m - s);
#pragma unroll
            for (int c = 0; c < 16; ++c) acc[c] *= r;
            l *= r; m = s;
        }
        float p = __expf(s - m);
        l += p;
        const float4* vr = (const float4*)(vb + y * 16);
        float4 v0 = vr[0], v1 = vr[1], v2 = vr[2], v3 = vr[3];
        acc[0] += p * v0.x;  acc[1] += p * v0.y;  acc[2] += p * v0.z;  acc[3] += p * v0.w;
        acc[4] += p * v1.x;  acc[5] += p * v1.y;  acc[6] += p * v1.z;  acc[7] += p * v1.w;
        acc[8] += p * v2.x;  acc[9] += p * v2.y;  acc[10] += p * v2.z; acc[11] += p * v2.w;
        acc[12] += p * v3.x; acc[13] += p * v3.y; acc[14] += p * v3.z; acc[15] += p * v3.w;
    }
    float inv = 1.f / l;

    const int b = bt / T_, t = bt - b * T_;
    unsigned int ou[8];
#pragma unroll
    for (int cu = 0; cu < 8; ++cu)
        ou[cu] = bf16rne(acc[2 * cu] * inv) | (bf16rne(acc[2 * cu + 1] * inv) << 16);
    unsigned int* dst = foutD + ((size_t)(b * F_ + f) * T_ + t) * 8;
    *(uint4*)dst       = make_uint4(ou[0], ou[1], ou[2], ou[3]);
    *(uint4*)(dst + 4) = make_uint4(ou[4], ou[5], ou[6], ou[7]);
}

// ---------------- Kernel C: causal t-attention, one block per (b,f) ----------------
// 192 threads; thread handles rows t1 = 191-tid and t2 = 192+tid (balanced: 448 row-iters/wave)
__global__ __launch_bounds__(192) void k_tattn(
    const unsigned int* __restrict__ tqkT, const unsigned int* __restrict__ foutD,
    float* __restrict__ tout)
{
    __shared__ float lds[18432];   // q[0..6144) k[6144..12288) f[12288..18432), each [t][16c]

    const int bf_ = blockIdx.x;
    const unsigned int* src = tqkT + (size_t)bf_ * 6144;
    for (int i = threadIdx.x; i < 6144; i += 192) {
        unsigned int u = src[i];
        float2 w2;
        w2.x = __uint_as_float(u << 16);
        w2.y = __uint_as_float(u & 0xffff0000u);
        *(float2*)&lds[2 * i] = w2;
    }
    const unsigned int* srcf = foutD + (size_t)bf_ * 3072;
    for (int i = threadIdx.x; i < 3072; i += 192) {
        unsigned int u = srcf[i];
        float2 w2;
        w2.x = __uint_as_float(u << 16);
        w2.y = __uint_as_float(u & 0xffff0000u);
        *(float2*)&lds[12288 + 2 * i] = w2;
    }
    __syncthreads();

    const int t1 = 191 - threadIdx.x;
    const int t2 = 192 + threadIdx.x;

    float q1[16], q2[16];
#pragma unroll
    for (int c = 0; c < 16; ++c) { q1[c] = lds[t1 * 16 + c]; q2[c] = lds[t2 * 16 + c]; }

    const float* kb = lds + 6144;
    const float* fb = lds + 12288;

    float m1 = -1e30f, l1 = 0.f, m2 = -1e30f, l2 = 0.f;
    float a1[16], a2[16];
#pragma unroll
    for (int c = 0; c < 16; ++c) { a1[c] = 0.f; a2[c] = 0.f; }

    for (int y = 0; y <= t2; ++y) {
        const float4* kr = (const float4*)(kb + y * 16);
        float4 k0 = kr[0], k1 = kr[1], k2 = kr[2], k3 = kr[3];
        const float4* fr = (const float4*)(fb + y * 16);
        float4 f0 = fr[0], f1 = fr[1], f2 = fr[2], f3 = fr[3];

        // row 2 (always active: y <= t2)
        {
            float s = q2[0] * k0.x + q2[1] * k0.y + q2[2] * k0.z + q2[3] * k0.w
                    + q2[4] * k1.x + q2[5] * k1.y + q2[6] * k1.z + q2[7] * k1.w
                    + q2[8] * k2.x + q2[9] * k2.y + q2[10] * k2.z + q2[11] * k2.w
                    + q2[12] * k3.x + q2[13] * k3.y + q2[14] * k3.z + q2[15] * k3.w;
            s *= 0.25f;
            if (s > m2) {
                float r = __expf(m2 - s);
#pragma unroll
                for (int c = 0; c < 16; ++c) a2[c] *= r;
                l2 *= r; m2 = s;
            }
            float p = __expf(s - m2);
            l2 += p;
            a2[0] += p * f0.x;  a2[1] += p * f0.y;  a2[2] += p * f0.z;  a2[3] += p * f0.w;
            a2[4] += p * f1.x;  a2[5] += p * f1.y;  a2[6] += p * f1.z;  a2[7] += p * f1.w;
            a2[8] += p * f2.x;  a2[9] += p * f2.y;  a2[10] += p * f2.z; a2[11] += p * f2.w;
            a2[12] += p * f3.x; a2[13] += p * f3.y; a2[14] += p * f3.z; a2[15] += p * f3.w;
        }
        if (y <= t1) {
            float s = q1[0] * k0.x + q1[1] * k0.y + q1[2] * k0.z + q1[3] * k0.w
                    + q1[4] * k1.x + q1[5] * k1.y + q1[6] * k1.z + q1[7] * k1.w
                    + q1[8] * k2.x + q1[9] * k2.y + q1[10] * k2.z + q1[11] * k2.w
                    + q1[12] * k3.x + q1[13] * k3.y + q1[14] * k3.z + q1[15] * k3.w;
            s *= 0.25f;
            if (s > m1) {
                float r = __expf(m1 - s);
#pragma unroll
                for (int c = 0; c < 16; ++c) a1[c] *= r;
                l1 *= r; m1 = s;
            }
            float p = __expf(s - m1);
            l1 += p;
            a1[0] += p * f0.x;  a1[1] += p * f0.y;  a1[2] += p * f0.z;  a1[3] += p * f0.w;
            a1[4] += p * f1.x;  a1[5] += p * f1.y;  a1[6] += p * f1.z;  a1[7] += p * f1.w;
            a1[8] += p * f2.x;  a1[9] += p * f2.y;  a1[10] += p * f2.z; a1[11] += p * f2.w;
            a1[12] += p * f3.x; a1[13] += p * f3.y; a1[14] += p * f3.z; a1[15] += p * f3.w;
        }
    }

    const float inv1 = 1.f / l1, inv2 = 1.f / l2;
    const int b = bf_ >> 8, f = bf_ & 255;
    float* dst = tout + (size_t)b * DC_ * SP_ + (size_t)f * T_;
#pragma unroll
    for (int c = 0; c < 16; ++c) {
        dst[(size_t)c * SP_ + t1] = a1[c] * inv1;
        dst[(size_t)c * SP_ + t2] = a2[c] * inv2;
    }
}

// ---------------- Kernel D: proj conv + BN + PReLU + residual ----------------
__global__ __launch_bounds__(256) void k_proj(
    const float* __restrict__ tout, const float* __restrict__ x,
    const float* __restrict__ pw, const float* __restrict__ g, const float* __restrict__ be,
    const float* __restrict__ mn, const float* __restrict__ va, const float* __restrict__ al,
    float* __restrict__ out)
{
    __shared__ float s_w[64 * 16];
    __shared__ float sc[64], bi[64], alp[64];

    const int tid = threadIdx.x;
    for (int i = tid; i < 64 * 16; i += 256) s_w[i] = pw[i];
    if (tid < 64) {
        float s = g[tid] * rsqrtf(va[tid] + EPSF);
        sc[tid] = s; bi[tid] = be[tid] - mn[tid] * s; alp[tid] = al[tid];
    }
    __syncthreads();

    const int pos = blockIdx.x * 256 + tid;
    const int b = pos / SP_;
    const int rem = pos - b * SP_;

    const float* tp = tout + (size_t)b * DC_ * SP_ + rem;
    float tr[16];
#pragma unroll
    for (int c = 0; c < 16; ++c) tr[c] = tp[(size_t)c * SP_];

    const float* xp = x + (size_t)b * CIN * SP_ + rem;
    float* op = out + (size_t)b * CIN * SP_ + rem;
    for (int o = 0; o < 64; ++o) {
        float acc = 0.f;
#pragma unroll
        for (int c = 0; c < 16; ++c) acc += s_w[o * 16 + c] * tr[c];
        float xn = acc * sc[o] + bi[o];
        xn = xn >= 0.f ? xn : alp[o] * xn;
        op[(size_t)o * SP_] = xn + xp[(size_t)o * SP_];
    }
}

extern "C" void kernel_launch(void* const* d_in, const int* in_sizes, int n_in,
                              void* d_out, int out_size, void* d_ws, size_t ws_size,
                              hipStream_t stream) {
    const float* x          = (const float*)d_in[0];
    const float* fqkv_w     = (const float*)d_in[1];
    const float* fqkv_gamma = (const float*)d_in[2];
    const float* fqkv_beta  = (const float*)d_in[3];
    const float* fqkv_mean  = (const float*)d_in[4];
    const float* fqkv_var   = (const float*)d_in[5];
    const float* fqkv_alpha = (const float*)d_in[6];
    const float* tqk_w      = (const float*)d_in[7];
    const float* tqk_gamma  = (const float*)d_in[8];
    const float* tqk_beta   = (const float*)d_in[9];
    const float* tqk_mean   = (const float*)d_in[10];
    const float* tqk_var    = (const float*)d_in[11];
    const float* tqk_alpha  = (const float*)d_in[12];
    const float* proj_w     = (const float*)d_in[13];
    const float* proj_gamma = (const float*)d_in[14];
    const float* proj_beta  = (const float*)d_in[15];
    const float* proj_mean  = (const float*)d_in[16];
    const float* proj_var   = (const float*)d_in[17];
    const float* proj_alpha = (const float*)d_in[18];

    unsigned int* fqkvT = (unsigned int*)d_ws;            // B*T*6144 u32 = 9,437,184 (36 MB)
    unsigned int* tqkT  = fqkvT + (size_t)B_ * T_ * 6144; // B*F*6144 u32 = 6,291,456 (24 MB)
    unsigned int* foutD = tqkT + (size_t)B_ * F_ * 6144;  // B*F*T*8  u32 = 3,145,728 (12 MB)
    float*        tout  = (float*)(foutD + (size_t)B_ * F_ * T_ * 8); // 6,291,456 f32 (24 MB)

    float* out = (float*)d_out;

    k_conv<<<B_ * 64 * 6, 256, 0, stream>>>(
        x, fqkv_w, fqkv_gamma, fqkv_beta, fqkv_mean, fqkv_var, fqkv_alpha,
        tqk_w, tqk_gamma, tqk_beta, tqk_mean, tqk_var, tqk_alpha, fqkvT, tqkT);

    k_fattn<<<B_ * T_, 256, 0, stream>>>(fqkvT, foutD);

    k_tattn<<<B_ * F_, 192, 0, stream>>>(tqkT, foutD, tout);

    k_proj<<<(B_ * SP_) / 256, 256, 0, stream>>>(
        tout, x, proj_w, proj_gamma, proj_beta, proj_mean, proj_var, proj_alpha, out);
}

// Round 3
// 706.034 us; speedup vs baseline: 1.3490x; 1.0608x over previous
//
#include <hip/hip_runtime.h>
#include <hip/hip_bf16.h>

// AxialSoftAttention: B=4, C=64, F=256, T=384, DC=16
//  k_conv : x -> fqkvT [b][t][{q,k,v}][f=256][16c] bf16   (36 MB)
//           x -> tqkT  [b][f][{q,k}][t=384][16c]  bf16    (24 MB)
//  k_fattn: fqkvT -> foutD [b][f][t=384][16c] bf16        (12 MB)  R=4 reg-blocked
//  k_tattn: tqkT,foutD -> toutP [b][f][t][16c] bf16       (12 MB)  R=3 reg-blocked causal
//  k_proj : toutP,x -> out fp32 (proj conv + BN + PReLU + residual)

#define B_   4
#define CIN  64
#define F_   256
#define T_   384
#define DC_  16
#define SP_  (F_ * T_)
#define EPSF 1e-5f

__device__ __forceinline__ unsigned int bf16rne(float f) {
    unsigned int u = __float_as_uint(f);
    return (u + 0x7fffu + ((u >> 16) & 1u)) >> 16;
}
__device__ __forceinline__ float blo(unsigned int u) { return __uint_as_float(u << 16); }
__device__ __forceinline__ float bhi(unsigned int u) { return __uint_as_float(u & 0xffff0000u); }
__device__ __forceinline__ void unpack8(uint4 u, float* o) {
    o[0] = blo(u.x); o[1] = bhi(u.x); o[2] = blo(u.y); o[3] = bhi(u.y);
    o[4] = blo(u.z); o[5] = bhi(u.z); o[6] = blo(u.w); o[7] = bhi(u.w);
}

// ---------------- Kernel A: conv + BN + PReLU + transpose-to-bf16 (unchanged) ----------------
__global__ __launch_bounds__(256) void k_conv(
    const float* __restrict__ x,
    const float* __restrict__ wf, const float* __restrict__ gf, const float* __restrict__ bf,
    const float* __restrict__ mf, const float* __restrict__ vf, const float* __restrict__ af,
    const float* __restrict__ wt, const float* __restrict__ gt, const float* __restrict__ bt,
    const float* __restrict__ mt, const float* __restrict__ vt, const float* __restrict__ at,
    unsigned int* __restrict__ fqkvT, unsigned int* __restrict__ tqkT)
{
    __shared__ float tile[16 * 260];

    const int bid = blockIdx.x;
    const int t0 = (bid % 6) * 64;
    const int f0 = ((bid / 6) & 63) * 4;
    const int b  = bid / 384;
    const int ff = threadIdx.x >> 6;
    const int tt = threadIdx.x & 63;
    const int f = f0 + ff, t = t0 + tt;

    const float* xp = x + (size_t)b * CIN * SP_ + (size_t)f * T_ + t;
    float xr[64];
#pragma unroll
    for (int c = 0; c < 64; ++c) xr[c] = xp[(size_t)c * SP_];

    for (int sec = 0; sec < 5; ++sec) {
        const bool isF = sec < 3;
        const float* w  = isF ? wf : wt;
        const float* g  = isF ? gf : gt;
        const float* be = isF ? bf : bt;
        const float* mn = isF ? mf : mt;
        const float* va = isF ? vf : vt;
        const float* al = isF ? af : at;
        const int ob = isF ? sec * 16 : (sec - 3) * 16;

        float acc[16];
#pragma unroll
        for (int i = 0; i < 16; ++i) {
            const float* wr = w + (size_t)(ob + i) * 64;
            float a = 0.f;
#pragma unroll
            for (int c = 0; c < 64; ++c) a += wr[c] * xr[c];
            float s  = g[ob + i] * rsqrtf(va[ob + i] + EPSF);
            float xn = a * s + (be[ob + i] - mn[ob + i] * s);
            acc[i] = xn >= 0.f ? xn : al[ob + i] * xn;
        }

        __syncthreads();
#pragma unroll
        for (int i = 0; i < 16; ++i) tile[i * 260 + ff * 65 + tt] = acc[i];
        __syncthreads();

        if (isF) {
            for (int j = threadIdx.x; j < 2048; j += 256) {
                int wtt = j >> 5;
                int r   = j & 31;
                int wff = r >> 3;
                int cu  = r & 7;
                unsigned int lo = bf16rne(tile[(2 * cu) * 260 + wff * 65 + wtt]);
                unsigned int hi = bf16rne(tile[(2 * cu + 1) * 260 + wff * 65 + wtt]);
                fqkvT[(size_t)(b * T_ + t0 + wtt) * 6144 + sec * 2048 + (f0 + wff) * 8 + cu] =
                    lo | (hi << 16);
            }
        } else {
            const int tsec = sec - 3;
            for (int j = threadIdx.x; j < 2048; j += 256) {
                int wff = j >> 9;
                int r   = j & 511;
                int wtt = r >> 3;
                int cu  = r & 7;
                unsigned int lo = bf16rne(tile[(2 * cu) * 260 + wff * 65 + wtt]);
                unsigned int hi = bf16rne(tile[(2 * cu + 1) * 260 + wff * 65 + wtt]);
                tqkT[(size_t)(b * F_ + f0 + wff) * 6144 + tsec * 3072 + (t0 + wtt) * 8 + cu] =
                    lo | (hi << 16);
            }
        }
    }
}

// ---------------- Kernel B: f-attention, R=4 register-blocked ----------------
// 128 threads = 2 wave-groups, each owning one (b,t). Thread: q-rows f = lane+64r.
__global__ __launch_bounds__(128) void k_fattn(
    const unsigned int* __restrict__ fqkvT, unsigned int* __restrict__ foutD)
{
    __shared__ unsigned int sk[2][2048];   // bf16-packed [y][16c]
    __shared__ unsigned int sv[2][2048];

    const int sub  = threadIdx.x >> 6;
    const int lane = threadIdx.x & 63;
    const int bt   = blockIdx.x * 2 + sub;
    const unsigned int* src = fqkvT + (size_t)bt * 6144;

    {
        const uint4* s4 = (const uint4*)(src + 2048);   // k(512 uint4) then v(512 uint4)
        uint4* k4 = (uint4*)sk[sub];
        uint4* v4 = (uint4*)sv[sub];
#pragma unroll
        for (int j = 0; j < 8; ++j) k4[lane + 64 * j] = s4[lane + 64 * j];
#pragma unroll
        for (int j = 0; j < 8; ++j) v4[lane + 64 * j] = s4[512 + lane + 64 * j];
    }

    float q[4][16];
#pragma unroll
    for (int r = 0; r < 4; ++r) {
        const uint4* qp = (const uint4*)(src + (lane + 64 * r) * 8);
        float tmp[16];
        unpack8(qp[0], tmp); unpack8(qp[1], tmp + 8);
#pragma unroll
        for (int c = 0; c < 16; ++c) q[r][c] = tmp[c] * 0.25f;
    }
    __syncthreads();

    float m[4], l[4], acc[4][16];
#pragma unroll
    for (int r = 0; r < 4; ++r) {
        m[r] = -1e30f; l[r] = 0.f;
#pragma unroll
        for (int c = 0; c < 16; ++c) acc[r][c] = 0.f;
    }

#pragma unroll 2
    for (int y = 0; y < F_; ++y) {
        uint4 ku0 = *(const uint4*)&sk[sub][y * 8];
        uint4 ku1 = *(const uint4*)&sk[sub][y * 8 + 4];
        uint4 vu0 = *(const uint4*)&sv[sub][y * 8];
        uint4 vu1 = *(const uint4*)&sv[sub][y * 8 + 4];
        float kk[16];
        unpack8(ku0, kk); unpack8(ku1, kk + 8);
        float s[4];
#pragma unroll
        for (int r = 0; r < 4; ++r) {
            float a = 0.f;
#pragma unroll
            for (int c = 0; c < 16; ++c) a += q[r][c] * kk[c];
            s[r] = a;
        }
        float vv[16];
        unpack8(vu0, vv); unpack8(vu1, vv + 8);
#pragma unroll
        for (int r = 0; r < 4; ++r) {
            if (s[r] > m[r]) {
                float rr = __expf(m[r] - s[r]);
#pragma unroll
                for (int c = 0; c < 16; ++c) acc[r][c] *= rr;
                l[r] *= rr; m[r] = s[r];
            }
            float p = __expf(s[r] - m[r]);
            l[r] += p;
#pragma unroll
            for (int c = 0; c < 16; ++c) acc[r][c] += p * vv[c];
        }
    }

    const int b = bt / T_, t = bt - b * T_;
#pragma unroll
    for (int r = 0; r < 4; ++r) {
        float inv = 1.f / l[r];
        const int f = lane + 64 * r;
        unsigned int ou[8];
#pragma unroll
        for (int cu = 0; cu < 8; ++cu)
            ou[cu] = bf16rne(acc[r][2 * cu] * inv) | (bf16rne(acc[r][2 * cu + 1] * inv) << 16);
        unsigned int* dst = foutD + ((size_t)(b * F_ + f) * T_ + t) * 8;
        *(uint4*)dst       = make_uint4(ou[0], ou[1], ou[2], ou[3]);
        *(uint4*)(dst + 4) = make_uint4(ou[4], ou[5], ou[6], ou[7]);
    }
}

// ---------------- Kernel C: causal t-attention, R=3 register-blocked ----------------
// 128 threads per (b,f). Thread rows t = 128r+tid. Band-uniform causal skip.
__global__ __launch_bounds__(128) void k_tattn(
    const unsigned int* __restrict__ tqkT, const unsigned int* __restrict__ foutD,
    unsigned int* __restrict__ toutP)
{
    __shared__ unsigned int skk[3072];   // kt packed [t][16c]
    __shared__ unsigned int sff[3072];   // f_out packed [t][16c]

    const int tid = threadIdx.x;
    const int bf_ = blockIdx.x;
    {
        const uint4* k4 = (const uint4*)(tqkT + (size_t)bf_ * 6144 + 3072);
        const uint4* f4 = (const uint4*)(foutD + (size_t)bf_ * 3072);
#pragma unroll
        for (int j = 0; j < 6; ++j) ((uint4*)skk)[tid + 128 * j] = k4[tid + 128 * j];
#pragma unroll
        for (int j = 0; j < 6; ++j) ((uint4*)sff)[tid + 128 * j] = f4[tid + 128 * j];
    }

    float q[3][16];
    const unsigned int* srcQ = tqkT + (size_t)bf_ * 6144;
#pragma unroll
    for (int r = 0; r < 3; ++r) {
        const uint4* qp = (const uint4*)(srcQ + (128 * r + tid) * 8);
        float tmp[16];
        unpack8(qp[0], tmp); unpack8(qp[1], tmp + 8);
#pragma unroll
        for (int c = 0; c < 16; ++c) q[r][c] = tmp[c] * 0.25f;
    }
    __syncthreads();

    float m[3], l[3], acc[3][16];
#pragma unroll
    for (int r = 0; r < 3; ++r) {
        m[r] = -1e30f; l[r] = 0.f;
#pragma unroll
        for (int c = 0; c < 16; ++c) acc[r][c] = 0.f;
    }

    for (int y = 0; y < T_; ++y) {
        const int rlo = y >> 7;          // bands below rlo are finished (wave-uniform)
        uint4 ku0 = *(const uint4*)&skk[y * 8];
        uint4 ku1 = *(const uint4*)&skk[y * 8 + 4];
        uint4 fu0 = *(const uint4*)&sff[y * 8];
        uint4 fu1 = *(const uint4*)&sff[y * 8 + 4];
        float kk[16], ff[16];
        unpack8(ku0, kk); unpack8(ku1, kk + 8);
        unpack8(fu0, ff); unpack8(fu1, ff + 8);
#pragma unroll
        for (int r = 0; r < 3; ++r) {
            if (r < rlo) continue;       // uniform skip of finished band
            float s = 0.f;
#pragma unroll
            for (int c = 0; c < 16; ++c) s += q[r][c] * kk[c];
            if (r == rlo) s = ((y & 127) > tid) ? -1e30f : s;   // causal mask on boundary band
            if (s > m[r]) {
                float rr = __expf(m[r] - s);
#pragma unroll
                for (int c = 0; c < 16; ++c) acc[r][c] *= rr;
                l[r] *= rr; m[r] = s;
            }
            float p = __expf(s - m[r]);
            l[r] += p;
#pragma unroll
            for (int c = 0; c < 16; ++c) acc[r][c] += p * ff[c];
        }
    }

#pragma unroll
    for (int r = 0; r < 3; ++r) {
        float inv = 1.f / l[r];
        unsigned int ou[8];
#pragma unroll
        for (int cu = 0; cu < 8; ++cu)
            ou[cu] = bf16rne(acc[r][2 * cu] * inv) | (bf16rne(acc[r][2 * cu + 1] * inv) << 16);
        unsigned int* dst = toutP + ((size_t)bf_ * T_ + 128 * r + tid) * 8;
        *(uint4*)dst       = make_uint4(ou[0], ou[1], ou[2], ou[3]);
        *(uint4*)(dst + 4) = make_uint4(ou[4], ou[5], ou[6], ou[7]);
    }
}

// ---------------- Kernel D: proj conv + BN + PReLU + residual ----------------
__global__ __launch_bounds__(256) void k_proj(
    const unsigned int* __restrict__ toutP, const float* __restrict__ x,
    const float* __restrict__ pw, const float* __restrict__ g, const float* __restrict__ be,
    const float* __restrict__ mn, const float* __restrict__ va, const float* __restrict__ al,
    float* __restrict__ out)
{
    __shared__ float s_w[64 * 16];
    __shared__ float sc[64], bi[64], alp[64];

    const int tid = threadIdx.x;
    for (int i = tid; i < 64 * 16; i += 256) s_w[i] = pw[i];
    if (tid < 64) {
        float s = g[tid] * rsqrtf(va[tid] + EPSF);
        sc[tid] = s; bi[tid] = be[tid] - mn[tid] * s; alp[tid] = al[tid];
    }
    __syncthreads();

    const int pos = blockIdx.x * 256 + tid;
    const int b = pos / SP_;
    const int rem = pos - b * SP_;

    const uint4* tp = (const uint4*)(toutP + (size_t)pos * 8);
    float tr[16];
    unpack8(tp[0], tr); unpack8(tp[1], tr + 8);

    const float* xp = x + (size_t)b * CIN * SP_ + rem;
    float* op = out + (size_t)b * CIN * SP_ + rem;
    for (int o = 0; o < 64; ++o) {
        float acc = 0.f;
#pragma unroll
        for (int c = 0; c < 16; ++c) acc += s_w[o * 16 + c] * tr[c];
        float xn = acc * sc[o] + bi[o];
        xn = xn >= 0.f ? xn : alp[o] * xn;
        op[(size_t)o * SP_] = xn + xp[(size_t)o * SP_];
    }
}

extern "C" void kernel_launch(void* const* d_in, const int* in_sizes, int n_in,
                              void* d_out, int out_size, void* d_ws, size_t ws_size,
                              hipStream_t stream) {
    const float* x          = (const float*)d_in[0];
    const float* fqkv_w     = (const float*)d_in[1];
    const float* fqkv_gamma = (const float*)d_in[2];
    const float* fqkv_beta  = (const float*)d_in[3];
    const float* fqkv_mean  = (const float*)d_in[4];
    const float* fqkv_var   = (const float*)d_in[5];
    const float* fqkv_alpha = (const float*)d_in[6];
    const float* tqk_w      = (const float*)d_in[7];
    const float* tqk_gamma  = (const float*)d_in[8];
    const float* tqk_beta   = (const float*)d_in[9];
    const float* tqk_mean   = (const float*)d_in[10];
    const float* tqk_var    = (const float*)d_in[11];
    const float* tqk_alpha  = (const float*)d_in[12];
    const float* proj_w     = (const float*)d_in[13];
    const float* proj_gamma = (const float*)d_in[14];
    const float* proj_beta  = (const float*)d_in[15];
    const float* proj_mean  = (const float*)d_in[16];
    const float* proj_var   = (const float*)d_in[17];
    const float* proj_alpha = (const float*)d_in[18];

    unsigned int* fqkvT = (unsigned int*)d_ws;            // 9,437,184 u32 (36 MB)
    unsigned int* tqkT  = fqkvT + (size_t)B_ * T_ * 6144; // 6,291,456 u32 (24 MB)
    unsigned int* foutD = tqkT + (size_t)B_ * F_ * 6144;  // 3,145,728 u32 (12 MB)
    unsigned int* toutP = foutD + (size_t)B_ * F_ * T_ * 8; // 3,145,728 u32 (12 MB)

    float* out = (float*)d_out;

    k_conv<<<B_ * 64 * 6, 256, 0, stream>>>(
        x, fqkv_w, fqkv_gamma, fqkv_beta, fqkv_mean, fqkv_var, fqkv_alpha,
        tqk_w, tqk_gamma, tqk_beta, tqk_mean, tqk_var, tqk_alpha, fqkvT, tqkT);

    k_fattn<<<B_ * T_ / 2, 128, 0, stream>>>(fqkvT, foutD);

    k_tattn<<<B_ * F_, 128, 0, stream>>>(tqkT, foutD, toutP);

    k_proj<<<(B_ * SP_) / 256, 256, 0, stream>>>(
        toutP, x, proj_w, proj_gamma, proj_beta, proj_mean, proj_var, proj_alpha, out);
}

// Round 7
// 449.653 us; speedup vs baseline: 2.1182x; 1.5702x over previous
//
#include <hip/hip_runtime.h>
#include <hip/hip_bf16.h>

// AxialSoftAttention: B=4, C=64, F=256, T=384, DC=16
//  k_conv : x -> fqkvT [b][t][{q,k,v}][f=256][16c] bf16   (36 MB)
//           x -> tqkT  [b][f][{q,k}][t=384][16c]  bf16    (24 MB)
//  k_fattn: MFMA flash attn over F, 1 wave per (b,t), no LDS
//  k_tattn: MFMA causal flash attn over T, 4 waves per (b,f)
//  k_proj : proj conv + BN + PReLU + residual (fp32 out)

#define B_   4
#define CIN  64
#define F_   256
#define T_   384
#define DC_  16
#define SP_  (F_ * T_)
#define EPSF 1e-5f

typedef unsigned int uint;
typedef __attribute__((ext_vector_type(8))) short bf16x8;
typedef __attribute__((ext_vector_type(4))) float f32x4;

#define MFMA16(A, B, C) __builtin_amdgcn_mfma_f32_16x16x32_bf16((A), (B), (C), 0, 0, 0)
#define C1SCALE 0.36067376022224085f   // 0.25 * log2(e)

union FragU { uint4 u; bf16x8 v; };
__device__ __forceinline__ bf16x8 asfrag(uint4 u) { FragU f; f.u = u; return f.v; }
__device__ __forceinline__ f32x4 fzero() { f32x4 z = {0.f, 0.f, 0.f, 0.f}; return z; }

__device__ __forceinline__ uint bf16rne(float f) {
    uint u = __float_as_uint(f);
    return (u + 0x7fffu + ((u >> 16) & 1u)) >> 16;
}

// Online-softmax update for one chunk of 8 score tiles (Sᵀ layout: col=lane&15 is
// the query, rows are y). Updates m (raw-score max), lsum, rescales o, packs P to bf16.
__device__ __forceinline__ void softmax_chunk(
    f32x4* c, float& m, float& lsum, f32x4& o, uint (*pk)[2])
{
    float cm = -3.0e38f;
#pragma unroll
    for (int ct = 0; ct < 8; ++ct) {
        float t0 = fmaxf(fmaxf(c[ct][0], c[ct][1]), fmaxf(c[ct][2], c[ct][3]));
        cm = fmaxf(cm, t0);
    }
    cm = fmaxf(cm, __shfl_xor(cm, 16));
    cm = fmaxf(cm, __shfl_xor(cm, 32));
    float mn = fmaxf(m, cm);
    float mC = mn * C1SCALE;
    float r = __builtin_amdgcn_exp2f(m * C1SCALE - mC);
    m = mn;
    float s_ = 0.f;
#pragma unroll
    for (int ct = 0; ct < 8; ++ct) {
        float p0 = __builtin_amdgcn_exp2f(fmaf(c[ct][0], C1SCALE, -mC));
        float p1 = __builtin_amdgcn_exp2f(fmaf(c[ct][1], C1SCALE, -mC));
        float p2 = __builtin_amdgcn_exp2f(fmaf(c[ct][2], C1SCALE, -mC));
        float p3 = __builtin_amdgcn_exp2f(fmaf(c[ct][3], C1SCALE, -mC));
        s_ += (p0 + p1) + (p2 + p3);
        pk[ct][0] = bf16rne(p0) | (bf16rne(p1) << 16);
        pk[ct][1] = bf16rne(p2) | (bf16rne(p3) << 16);
    }
    s_ += __shfl_xor(s_, 16);
    s_ += __shfl_xor(s_, 32);
    lsum = lsum * r + s_;
    o *= r;
}

// Regroup packed P (C-layout) into the PV B-fragment for K-step ysl, then MFMA.
// word p2 <- pk[2*ysl + (q>>1)][p2&1] from lane (lane16 + 16*(2*(q&1) + (p2>>1))).
__device__ __forceinline__ f32x4 pv_step(
    const uint (*pk)[2], int ysl, int srcA, int srcB, bool hiT, uint4 a2, f32x4 o)
{
    uint t00 = (uint)__shfl((int)pk[2*ysl][0],   srcA);
    uint t01 = (uint)__shfl((int)pk[2*ysl+1][0], srcA);
    uint t10 = (uint)__shfl((int)pk[2*ysl][1],   srcA);
    uint t11 = (uint)__shfl((int)pk[2*ysl+1][1], srcA);
    uint t20 = (uint)__shfl((int)pk[2*ysl][0],   srcB);
    uint t21 = (uint)__shfl((int)pk[2*ysl+1][0], srcB);
    uint t30 = (uint)__shfl((int)pk[2*ysl][1],   srcB);
    uint t31 = (uint)__shfl((int)pk[2*ysl+1][1], srcB);
    uint4 b2;
    b2.x = hiT ? t01 : t00;
    b2.y = hiT ? t11 : t10;
    b2.z = hiT ? t21 : t20;
    b2.w = hiT ? t31 : t30;
    return MFMA16(asfrag(a2), asfrag(b2), o);
}

// ---------------- Kernel A: conv + BN + PReLU + transpose-to-bf16 (unchanged) ----------------
__global__ __launch_bounds__(256) void k_conv(
    const float* __restrict__ x,
    const float* __restrict__ wf, const float* __restrict__ gf, const float* __restrict__ bf,
    const float* __restrict__ mf, const float* __restrict__ vf, const float* __restrict__ af,
    const float* __restrict__ wt, const float* __restrict__ gt, const float* __restrict__ bt,
    const float* __restrict__ mt, const float* __restrict__ vt, const float* __restrict__ at,
    uint* __restrict__ fqkvT, uint* __restrict__ tqkT)
{
    __shared__ float tile[16 * 260];

    const int bid = blockIdx.x;
    const int t0 = (bid % 6) * 64;
    const int f0 = ((bid / 6) & 63) * 4;
    const int b  = bid / 384;
    const int ff = threadIdx.x >> 6;
    const int tt = threadIdx.x & 63;
    const int f = f0 + ff, t = t0 + tt;

    const float* xp = x + (size_t)b * CIN * SP_ + (size_t)f * T_ + t;
    float xr[64];
#pragma unroll
    for (int c = 0; c < 64; ++c) xr[c] = xp[(size_t)c * SP_];

    for (int sec = 0; sec < 5; ++sec) {
        const bool isF = sec < 3;
        const float* w  = isF ? wf : wt;
        const float* g  = isF ? gf : gt;
        const float* be = isF ? bf : bt;
        const float* mn = isF ? mf : mt;
        const float* va = isF ? vf : vt;
        const float* al = isF ? af : at;
        const int ob = isF ? sec * 16 : (sec - 3) * 16;

        float acc[16];
#pragma unroll
        for (int i = 0; i < 16; ++i) {
            const float* wr = w + (size_t)(ob + i) * 64;
            float a = 0.f;
#pragma unroll
            for (int c = 0; c < 64; ++c) a += wr[c] * xr[c];
            float s  = g[ob + i] * rsqrtf(va[ob + i] + EPSF);
            float xn = a * s + (be[ob + i] - mn[ob + i] * s);
            acc[i] = xn >= 0.f ? xn : al[ob + i] * xn;
        }

        __syncthreads();
#pragma unroll
        for (int i = 0; i < 16; ++i) tile[i * 260 + ff * 65 + tt] = acc[i];
        __syncthreads();

        if (isF) {
            for (int j = threadIdx.x; j < 2048; j += 256) {
                int wtt = j >> 5;
                int r   = j & 31;
                int wff = r >> 3;
                int cu  = r & 7;
                uint lo = bf16rne(tile[(2 * cu) * 260 + wff * 65 + wtt]);
                uint hi = bf16rne(tile[(2 * cu + 1) * 260 + wff * 65 + wtt]);
                fqkvT[(size_t)(b * T_ + t0 + wtt) * 6144 + sec * 2048 + (f0 + wff) * 8 + cu] =
                    lo | (hi << 16);
            }
        } else {
            const int tsec = sec - 3;
            for (int j = threadIdx.x; j < 2048; j += 256) {
                int wff = j >> 9;
                int r   = j & 511;
                int wtt = r >> 3;
                int cu  = r & 7;
                uint lo = bf16rne(tile[(2 * cu) * 260 + wff * 65 + wtt]);
                uint hi = bf16rne(tile[(2 * cu + 1) * 260 + wff * 65 + wtt]);
                tqkT[(size_t)(b * F_ + f0 + wff) * 6144 + tsec * 3072 + (t0 + wtt) * 8 + cu] =
                    lo | (hi << 16);
            }
        }
    }
}

// ---------------- Kernel B: MFMA f-attention, 1 wave per (b,t), no LDS ----------------
__global__ __launch_bounds__(64) void k_fattn(
    const uint* __restrict__ fqkvT, uint* __restrict__ foutD)
{
    const int wid = blockIdx.x;                 // b*T + t
    const int lane = threadIdx.x;
    const int lane16 = lane & 15, q = lane >> 4;
    const bool lo2 = q < 2;
    const uint* base = fqkvT + (size_t)wid * 6144;

    // K A-fragments (m = y-in-tile, k = channel; channels 16..31 are zero pad)
    uint4 kf[16];
#pragma unroll
    for (int yt = 0; yt < 16; ++yt) {
        kf[yt] = make_uint4(0, 0, 0, 0);
        if (lo2) kf[yt] = *(const uint4*)(base + 2048 + (yt * 16 + lane16) * 8 + 4 * q);
    }
    // V A-fragments for PV (m = channel = lane16, k = y): u16 gathers, resident
    const unsigned short* vp = (const unsigned short*)(base + 4096);
    uint4 vfr[8];
#pragma unroll
    for (int ys = 0; ys < 8; ++ys) {
        uint wv[4];
#pragma unroll
        for (int p2 = 0; p2 < 4; ++p2) {
            int y = 32 * ys + 8 * q + 2 * p2;
            wv[p2] = (uint)vp[y * 16 + lane16] | ((uint)vp[(y + 1) * 16 + lane16] << 16);
        }
        vfr[ys] = make_uint4(wv[0], wv[1], wv[2], wv[3]);
    }

    const int b = wid / T_, t = wid - b * T_;
    const int srcA = lane16 + 32 * (q & 1);
    const int srcB = srcA + 16;
    const bool hiT = q >= 2;

    for (int ft = 0; ft < 16; ++ft) {
        uint4 qf = make_uint4(0, 0, 0, 0);
        if (lo2) qf = *(const uint4*)(base + (ft * 16 + lane16) * 8 + 4 * q);

        float m = -3.0e38f, lsum = 0.f;
        f32x4 o = fzero();
#pragma unroll
        for (int ch = 0; ch < 2; ++ch) {
            f32x4 c[8];
#pragma unroll
            for (int ct = 0; ct < 8; ++ct)
                c[ct] = MFMA16(asfrag(kf[8 * ch + ct]), asfrag(qf), fzero());
            uint pk[8][2];
            softmax_chunk(c, m, lsum, o, pk);
#pragma unroll
            for (int ysl = 0; ysl < 4; ++ysl)
                o = pv_step(pk, ysl, srcA, srcB, hiT, vfr[4 * ch + ysl], o);
        }
        float inv = 1.f / lsum;
        o *= inv;
        uint2 wv2;
        wv2.x = bf16rne(o[0]) | (bf16rne(o[1]) << 16);
        wv2.y = bf16rne(o[2]) | (bf16rne(o[3]) << 16);
        *(uint2*)(foutD + ((size_t)(b * F_ + ft * 16 + lane16) * T_ + t) * 8 + 2 * q) = wv2;
    }
}

// ---------------- Kernel C: MFMA causal t-attention, 4 waves per (b,f) ----------------
__global__ __launch_bounds__(256) void k_tattn(
    const uint* __restrict__ tqkT, const uint* __restrict__ foutD,
    uint* __restrict__ toutP)
{
    __shared__ __align__(16) uint qk_lds[6144];   // qt [0,3072) kt [3072,6144), [t][16c]
    __shared__ __align__(16) uint fo_lds[3072];   // f_out [t][16c]

    const int bf_ = blockIdx.x;
    const int tid = threadIdx.x;
    {
        const uint4* s4 = (const uint4*)(tqkT + (size_t)bf_ * 6144);
        const uint4* f4 = (const uint4*)(foutD + (size_t)bf_ * 3072);
#pragma unroll
        for (int i = 0; i < 6; ++i) ((uint4*)qk_lds)[tid + 256 * i] = s4[tid + 256 * i];
#pragma unroll
        for (int i = 0; i < 3; ++i) ((uint4*)fo_lds)[tid + 256 * i] = f4[tid + 256 * i];
    }
    __syncthreads();

    const int w = tid >> 6;
    const int lane = tid & 63;
    const int lane16 = lane & 15, q = lane >> 4;
    const bool lo2 = q < 2;
    const int srcA = lane16 + 32 * (q & 1);
    const int srcB = srcA + 16;
    const bool hiT = q >= 2;

    // f_out A-fragments (m = channel, k = y), resident: 12 K-steps
    const unsigned short* fp = (const unsigned short*)fo_lds;
    uint4 a2[12];
#pragma unroll
    for (int ys = 0; ys < 12; ++ys) {
        uint wv[4];
#pragma unroll
        for (int p2 = 0; p2 < 4; ++p2) {
            int y = 32 * ys + 8 * q + 2 * p2;
            wv[p2] = (uint)fp[y * 16 + lane16] | ((uint)fp[(y + 1) * 16 + lane16] << 16);
        }
        a2[ys] = make_uint4(wv[0], wv[1], wv[2], wv[3]);
    }

    // balanced strips: wave w handles s = 8*(kk>>1) + (kk&1 ? 7-w : w), kk=0..5
    for (int kk = 0; kk < 6; ++kk) {
        const int s = 8 * (kk >> 1) + ((kk & 1) ? 7 - w : w);

        uint4 qf = make_uint4(0, 0, 0, 0);
        if (lo2) qf = *(const uint4*)&qk_lds[(s * 16 + lane16) * 8 + 4 * q];

        float m = -3.0e38f, lsum = 0.f;
        f32x4 o = fzero();
#pragma unroll
        for (int c0 = 0; c0 < 24; c0 += 8) {
            if (c0 <= s) {
                const int ntile = min(8, s + 1 - c0);
                f32x4 c[8];
#pragma unroll
                for (int ct = 0; ct < 8; ++ct) {
                    if (ct < ntile) {
                        uint4 ak = make_uint4(0, 0, 0, 0);
                        if (lo2) ak = *(const uint4*)&qk_lds[3072 + ((c0 + ct) * 16 + lane16) * 8 + 4 * q];
                        c[ct] = MFMA16(asfrag(ak), asfrag(qf), fzero());
                        if (c0 + ct == s) {   // diagonal tile: mask y > t
#pragma unroll
                            for (int i = 0; i < 4; ++i)
                                c[ct][i] = (4 * q + i > lane16) ? -3.0e38f : c[ct][i];
                        }
                    } else {
                        f32x4 neg = {-3.0e38f, -3.0e38f, -3.0e38f, -3.0e38f};
                        c[ct] = neg;
                    }
                }
                uint pk[8][2];
                softmax_chunk(c, m, lsum, o, pk);
#pragma unroll
                for (int ysl = 0; ysl < 4; ++ysl) {
                    if (2 * ysl < ntile)
                        o = pv_step(pk, ysl, srcA, srcB, hiT, a2[c0 / 2 + ysl], o);
                }
            }
        }
        float inv = 1.f / lsum;
        o *= inv;
        uint2 wv2;
        wv2.x = bf16rne(o[0]) | (bf16rne(o[1]) << 16);
        wv2.y = bf16rne(o[2]) | (bf16rne(o[3]) << 16);
        *(uint2*)(toutP + ((size_t)bf_ * T_ + s * 16 + lane16) * 8 + 2 * q) = wv2;
    }
}

// ---------------- Kernel D: proj conv + BN + PReLU + residual (unchanged) ----------------
__global__ __launch_bounds__(256) void k_proj(
    const uint* __restrict__ toutP, const float* __restrict__ x,
    const float* __restrict__ pw, const float* __restrict__ g, const float* __restrict__ be,
    const float* __restrict__ mn, const float* __restrict__ va, const float* __restrict__ al,
    float* __restrict__ out)
{
    __shared__ float s_w[64 * 16];
    __shared__ float sc[64], bi[64], alp[64];

    const int tid = threadIdx.x;
    for (int i = tid; i < 64 * 16; i += 256) s_w[i] = pw[i];
    if (tid < 64) {
        float s = g[tid] * rsqrtf(va[tid] + EPSF);
        sc[tid] = s; bi[tid] = be[tid] - mn[tid] * s; alp[tid] = al[tid];
    }
    __syncthreads();

    const int pos = blockIdx.x * 256 + tid;
    const int b = pos / SP_;
    const int rem = pos - b * SP_;

    const uint4* tp = (const uint4*)(toutP + (size_t)pos * 8);
    uint4 u0 = tp[0], u1 = tp[1];
    float tr[16];
    tr[0] = __uint_as_float(u0.x << 16); tr[1] = __uint_as_float(u0.x & 0xffff0000u);
    tr[2] = __uint_as_float(u0.y << 16); tr[3] = __uint_as_float(u0.y & 0xffff0000u);
    tr[4] = __uint_as_float(u0.z << 16); tr[5] = __uint_as_float(u0.z & 0xffff0000u);
    tr[6] = __uint_as_float(u0.w << 16); tr[7] = __uint_as_float(u0.w & 0xffff0000u);
    tr[8] = __uint_as_float(u1.x << 16); tr[9] = __uint_as_float(u1.x & 0xffff0000u);
    tr[10] = __uint_as_float(u1.y << 16); tr[11] = __uint_as_float(u1.y & 0xffff0000u);
    tr[12] = __uint_as_float(u1.z << 16); tr[13] = __uint_as_float(u1.z & 0xffff0000u);
    tr[14] = __uint_as_float(u1.w << 16); tr[15] = __uint_as_float(u1.w & 0xffff0000u);

    const float* xp = x + (size_t)b * CIN * SP_ + rem;
    float* op = out + (size_t)b * CIN * SP_ + rem;
    for (int o = 0; o < 64; ++o) {
        float acc = 0.f;
#pragma unroll
        for (int c = 0; c < 16; ++c) acc += s_w[o * 16 + c] * tr[c];
        float xn = acc * sc[o] + bi[o];
        xn = xn >= 0.f ? xn : alp[o] * xn;
        op[(size_t)o * SP_] = xn + xp[(size_t)o * SP_];
    }
}

extern "C" void kernel_launch(void* const* d_in, const int* in_sizes, int n_in,
                              void* d_out, int out_size, void* d_ws, size_t ws_size,
                              hipStream_t stream) {
    const float* x          = (const float*)d_in[0];
    const float* fqkv_w     = (const float*)d_in[1];
    const float* fqkv_gamma = (const float*)d_in[2];
    const float* fqkv_beta  = (const float*)d_in[3];
    const float* fqkv_mean  = (const float*)d_in[4];
    const float* fqkv_var   = (const float*)d_in[5];
    const float* fqkv_alpha = (const float*)d_in[6];
    const float* tqk_w      = (const float*)d_in[7];
    const float* tqk_gamma  = (const float*)d_in[8];
    const float* tqk_beta   = (const float*)d_in[9];
    const float* tqk_mean   = (const float*)d_in[10];
    const float* tqk_var    = (const float*)d_in[11];
    const float* tqk_alpha  = (const float*)d_in[12];
    const float* proj_w     = (const float*)d_in[13];
    const float* proj_gamma = (const float*)d_in[14];
    const float* proj_beta  = (const float*)d_in[15];
    const float* proj_mean  = (const float*)d_in[16];
    const float* proj_var   = (const float*)d_in[17];
    const float* proj_alpha = (const float*)d_in[18];

    uint* fqkvT = (uint*)d_ws;                       // 9,437,184 u32 (36 MB)
    uint* tqkT  = fqkvT + (size_t)B_ * T_ * 6144;    // 6,291,456 u32 (24 MB)
    uint* foutD = tqkT + (size_t)B_ * F_ * 6144;     // 3,145,728 u32 (12 MB)
    uint* toutP = foutD + (size_t)B_ * F_ * T_ * 8;  // 3,145,728 u32 (12 MB)

    float* out = (float*)d_out;

    k_conv<<<B_ * 64 * 6, 256, 0, stream>>>(
        x, fqkv_w, fqkv_gamma, fqkv_beta, fqkv_mean, fqkv_var, fqkv_alpha,
        tqk_w, tqk_gamma, tqk_beta, tqk_mean, tqk_var, tqk_alpha, fqkvT, tqkT);

    k_fattn<<<B_ * T_, 64, 0, stream>>>(fqkvT, foutD);

    k_tattn<<<B_ * F_, 256, 0, stream>>>(tqkT, foutD, toutP);

    k_proj<<<(B_ * SP_) / 256, 256, 0, stream>>>(
        toutP, x, proj_w, proj_gamma, proj_beta, proj_mean, proj_var, proj_alpha, out);
}